// Round 1
// baseline (18227.213 us; speedup 1.0000x reference)
//
#include <hip/hip_runtime.h>
#include <cstdint>
#include <cstddef>

#define TT 512
#define BB 64
#define II 256
#define HH 512
#define GG 1536   // 3*H
#define OO 64
#define WSCAN 128 // scan workgroups; each owns 4 H-columns (12 rows of h2h_w)

// ---------------- Phase A: x_proj ----------------
// xp[t][g][b] = sum_k x[t][b][k] * x2h_w[g][k] + x2h_b[g]
// (layout [T][3H][B] so the scan reads contiguous b-runs)
__global__ __launch_bounds__(256)
void xproj_kernel(const float* __restrict__ x, const float* __restrict__ w,
                  const float* __restrict__ xb, float* __restrict__ xp)
{
    __shared__ float xs[64][68]; // [b][k-chunk] pad->16B aligned rows
    __shared__ float ws[64][68]; // [g][k-chunk]
    const int t  = blockIdx.y;
    const int g0 = blockIdx.x * 64;
    const int tid = threadIdx.x;
    const int gq = tid >> 4;   // 0..15
    const int bq = tid & 15;   // 0..15
    float acc[4][4];
#pragma unroll
    for (int j = 0; j < 4; ++j)
#pragma unroll
        for (int i = 0; i < 4; ++i) acc[j][i] = 0.f;

    for (int kc = 0; kc < 4; ++kc) {
        const int k0 = kc * 64;
        __syncthreads();
        for (int idx = tid; idx < 1024; idx += 256) {
            int r = idx >> 4, c4 = (idx & 15) * 4;
            float4 v = *(const float4*)(x + ((size_t)t * BB + r) * II + k0 + c4);
            xs[r][c4] = v.x; xs[r][c4+1] = v.y; xs[r][c4+2] = v.z; xs[r][c4+3] = v.w;
            float4 u = *(const float4*)(w + (size_t)(g0 + r) * II + k0 + c4);
            ws[r][c4] = u.x; ws[r][c4+1] = u.y; ws[r][c4+2] = u.z; ws[r][c4+3] = u.w;
        }
        __syncthreads();
#pragma unroll 4
        for (int k4 = 0; k4 < 16; ++k4) {
            float4 xv[4], wv[4];
#pragma unroll
            for (int i = 0; i < 4; ++i)
                xv[i] = *(const float4*)&xs[bq + 16*i][k4*4];
#pragma unroll
            for (int j = 0; j < 4; ++j)
                wv[j] = *(const float4*)&ws[gq + 16*j][k4*4];
#pragma unroll
            for (int j = 0; j < 4; ++j)
#pragma unroll
                for (int i = 0; i < 4; ++i) {
                    acc[j][i] = fmaf(wv[j].x, xv[i].x, acc[j][i]);
                    acc[j][i] = fmaf(wv[j].y, xv[i].y, acc[j][i]);
                    acc[j][i] = fmaf(wv[j].z, xv[i].z, acc[j][i]);
                    acc[j][i] = fmaf(wv[j].w, xv[i].w, acc[j][i]);
                }
        }
    }
#pragma unroll
    for (int j = 0; j < 4; ++j) {
        int g = g0 + gq + 16*j;
        float bg = xb[g];
#pragma unroll
        for (int i = 0; i < 4; ++i) {
            int b = bq + 16*i;
            xp[((size_t)t * GG + g) * BB + b] = acc[j][i] + bg;
        }
    }
}

// ---------------- Phase B: persistent GRU scan ----------------
// 128 WGs x 512 threads. WG j owns H-columns [4j, 4j+4). The rnn_activity
// output region is the state history (each step writes a fresh slot -> no
// WAR hazard). Sync: tag[j] = #steps WG j completed; release-store after
// write, per-thread acquire-poll before consuming. Bounded spin => no hang.
__global__ __launch_bounds__(512)
void scan_kernel(const float* __restrict__ xp, const float* __restrict__ hw,
                 const float* __restrict__ hbias, float* __restrict__ rnn,
                 int* __restrict__ tags)
{
    __shared__ float wl[3][4][516]; // [gate][c][k], pad 516 breaks bank aliasing
    const int j  = blockIdx.x;
    const int c0 = j * 4;
    const int tid = threadIdx.x;
    const int c    = tid & 3;        // column within chunk
    const int half = (tid >> 2) & 1; // k-half (0: k<256, 1: k>=256)
    const int b    = tid >> 3;       // 0..63

    for (int idx = tid; idx < 12 * 128; idx += 512) {
        int row = idx >> 7, pos = (idx & 127) * 4;
        int g = row >> 2, cc = row & 3;
        float4 v = *(const float4*)(hw + (size_t)(g * HH + c0 + cc) * HH + pos);
        wl[g][cc][pos]   = v.x; wl[g][cc][pos+1] = v.y;
        wl[g][cc][pos+2] = v.z; wl[g][cc][pos+3] = v.w;
    }
    const int col = c0 + c;
    const float bhr = hbias[col];
    const float bhu = hbias[HH + col];
    const float bhn = hbias[2*HH + col];
    __syncthreads();

    long long budget = 50000000; // total spin budget: deadlock -> finish wrong, not hang
    for (int t = 0; t < TT; ++t) {
        if (t > 0) {
            if (tid < WSCAN) {
                while (__hip_atomic_load(&tags[tid], __ATOMIC_ACQUIRE,
                                         __HIP_MEMORY_SCOPE_AGENT) < t) {
                    if (--budget < 0) break;
                }
            }
            __syncthreads();
            __threadfence(); // acquire at device scope for all threads
        }
        float ar = 0.f, au = 0.f, an = 0.f;
        if (t > 0) {
            const float* hp = rnn + ((size_t)(t-1) * BB + b) * HH + half * 256;
            const float* wr = &wl[0][c][half*256];
            const float* wu = &wl[1][c][half*256];
            const float* wn = &wl[2][c][half*256];
#pragma unroll 8
            for (int k = 0; k < 256; k += 4) {
                float4 h4 = *(const float4*)(hp + k);
                float4 a4 = *(const float4*)(wr + k);
                float4 b4 = *(const float4*)(wu + k);
                float4 c4 = *(const float4*)(wn + k);
                ar = fmaf(h4.x, a4.x, ar); ar = fmaf(h4.y, a4.y, ar);
                ar = fmaf(h4.z, a4.z, ar); ar = fmaf(h4.w, a4.w, ar);
                au = fmaf(h4.x, b4.x, au); au = fmaf(h4.y, b4.y, au);
                au = fmaf(h4.z, b4.z, au); au = fmaf(h4.w, b4.w, au);
                an = fmaf(h4.x, c4.x, an); an = fmaf(h4.y, c4.y, an);
                an = fmaf(h4.z, c4.z, an); an = fmaf(h4.w, c4.w, an);
            }
            // combine the two k-halves (partner lane differs in bit 2)
            ar += __shfl_xor(ar, 4, 64);
            au += __shfl_xor(au, 4, 64);
            an += __shfl_xor(an, 4, 64);
        }
        if (half == 0) {
            const size_t xbase = (size_t)t * GG * BB;
            float xr = xp[xbase + (size_t)(0*HH + col) * BB + b];
            float xu = xp[xbase + (size_t)(1*HH + col) * BB + b];
            float xn = xp[xbase + (size_t)(2*HH + col) * BB + b];
            float hprev = (t > 0) ? rnn[((size_t)(t-1) * BB + b) * HH + col] : 0.f;
            float r = 1.f / (1.f + __expf(-(xr + ar + bhr)));
            float u = 1.f / (1.f + __expf(-(xu + au + bhu)));
            // NOTE: h2h bias of n-gate is INSIDE reset*(...), per reference
            float npre = xn + r * (an + bhn);
            float e  = __expf(-2.f * npre);
            float nv = 2.f / (1.f + e) - 1.f;  // tanh, safe at +-inf
            float hy = u * hprev + (1.f - u) * nv;
            rnn[((size_t)t * BB + b) * HH + col] = hy;
        }
        __syncthreads();
        if (tid == 0) {
            __threadfence(); // release: drain block's writes past L2
            __hip_atomic_store(&tags[j], t + 1, __ATOMIC_RELEASE,
                               __HIP_MEMORY_SCOPE_AGENT);
        }
    }
}

// ---------------- Phase C: fc output ----------------
// out[t][b][o] = dot(rnn[t][b][:], fc_w[o][:]) + fc_b[o]
__global__ __launch_bounds__(256)
void fc_kernel(const float* __restrict__ rnn, const float* __restrict__ fcw,
               const float* __restrict__ fcb, float* __restrict__ out)
{
    __shared__ float wlds[128][65]; // [k][o]
    const int t = blockIdx.x;
    const int tid = threadIdx.x;
    const int o  = tid & 63;
    const int bg = tid >> 6; // 0..3 -> 16 b's each
    float acc[16];
#pragma unroll
    for (int i = 0; i < 16; ++i) acc[i] = 0.f;

    for (int kc = 0; kc < 4; ++kc) {
        const int k0 = kc * 128;
        __syncthreads();
        for (int idx = tid; idx < 64 * 32; idx += 256) {
            int oo = idx >> 5, kq = (idx & 31) * 4;
            float4 v = *(const float4*)(fcw + (size_t)oo * HH + k0 + kq);
            wlds[kq][oo] = v.x; wlds[kq+1][oo] = v.y;
            wlds[kq+2][oo] = v.z; wlds[kq+3][oo] = v.w;
        }
        __syncthreads();
#pragma unroll 2
        for (int k4 = 0; k4 < 32; ++k4) {
            float w0 = wlds[k4*4+0][o], w1 = wlds[k4*4+1][o];
            float w2 = wlds[k4*4+2][o], w3 = wlds[k4*4+3][o];
#pragma unroll
            for (int i = 0; i < 16; ++i) {
                int bb = bg * 16 + i;
                float4 h4 = *(const float4*)(rnn + ((size_t)t * BB + bb) * HH + k0 + k4*4);
                acc[i] = fmaf(h4.x, w0, fmaf(h4.y, w1, fmaf(h4.z, w2, fmaf(h4.w, w3, acc[i]))));
            }
        }
    }
    float bo = fcb[o];
#pragma unroll
    for (int i = 0; i < 16; ++i) {
        int bb = bg * 16 + i;
        out[((size_t)t * BB + bb) * OO + o] = acc[i] + bo;
    }
}

extern "C" void kernel_launch(void* const* d_in, const int* in_sizes, int n_in,
                              void* d_out, int out_size, void* d_ws, size_t ws_size,
                              hipStream_t stream)
{
    const float* x     = (const float*)d_in[0];
    const float* x2h_w = (const float*)d_in[1];
    const float* x2h_b = (const float*)d_in[2];
    const float* h2h_w = (const float*)d_in[3];
    const float* h2h_b = (const float*)d_in[4];
    const float* fc_w  = (const float*)d_in[5];
    const float* fc_b  = (const float*)d_in[6];

    float* out = (float*)d_out;                        // [T][B][O]
    float* rnn = (float*)d_out + (size_t)TT * BB * OO; // [T][B][H] (also scan state)

    float* xp = (float*)d_ws;                          // [T][3H][B] fp32
    const size_t xp_bytes = (size_t)TT * GG * BB * sizeof(float); // 201.3 MB
    int* tags = (int*)((char*)d_ws + xp_bytes);

    hipMemsetAsync(tags, 0, WSCAN * sizeof(int), stream);

    dim3 gA(GG / 64, TT);
    xproj_kernel<<<gA, 256, 0, stream>>>(x, x2h_w, x2h_b, xp);
    scan_kernel<<<WSCAN, 512, 0, stream>>>(xp, h2h_w, h2h_b, rnn, tags);
    fc_kernel<<<TT, 256, 0, stream>>>(rnn, fc_w, fc_b, out);
}

// Round 2
// 6198.134 us; speedup vs baseline: 2.9408x; 2.9408x over previous
//
#include <hip/hip_runtime.h>
#include <cstdint>
#include <cstddef>

typedef float f32x4 __attribute__((ext_vector_type(4)));

#define TT 512
#define BB 64
#define II 256
#define HH 512
#define GG 1536   // 3*H
#define OO 64
#define WSCAN 128 // scan workgroups; each owns 4 H-columns
#define TAGPAD 16 // dwords between tags (64B -> distinct LLC lines)

// ---------------- Phase A: x_proj ----------------
__global__ __launch_bounds__(256)
void xproj_kernel(const float* __restrict__ x, const float* __restrict__ w,
                  const float* __restrict__ xb, float* __restrict__ xp)
{
    __shared__ float xs[64][68];
    __shared__ float ws[64][68];
    const int t  = blockIdx.y;
    const int g0 = blockIdx.x * 64;
    const int tid = threadIdx.x;
    const int gq = tid >> 4;
    const int bq = tid & 15;
    float acc[4][4];
#pragma unroll
    for (int j = 0; j < 4; ++j)
#pragma unroll
        for (int i = 0; i < 4; ++i) acc[j][i] = 0.f;

    for (int kc = 0; kc < 4; ++kc) {
        const int k0 = kc * 64;
        __syncthreads();
        for (int idx = tid; idx < 1024; idx += 256) {
            int r = idx >> 4, c4 = (idx & 15) * 4;
            float4 v = *(const float4*)(x + ((size_t)t * BB + r) * II + k0 + c4);
            xs[r][c4] = v.x; xs[r][c4+1] = v.y; xs[r][c4+2] = v.z; xs[r][c4+3] = v.w;
            float4 u = *(const float4*)(w + (size_t)(g0 + r) * II + k0 + c4);
            ws[r][c4] = u.x; ws[r][c4+1] = u.y; ws[r][c4+2] = u.z; ws[r][c4+3] = u.w;
        }
        __syncthreads();
#pragma unroll 4
        for (int k4 = 0; k4 < 16; ++k4) {
            float4 xv[4], wv[4];
#pragma unroll
            for (int i = 0; i < 4; ++i)
                xv[i] = *(const float4*)&xs[bq + 16*i][k4*4];
#pragma unroll
            for (int j = 0; j < 4; ++j)
                wv[j] = *(const float4*)&ws[gq + 16*j][k4*4];
#pragma unroll
            for (int j = 0; j < 4; ++j)
#pragma unroll
                for (int i = 0; i < 4; ++i) {
                    acc[j][i] = fmaf(wv[j].x, xv[i].x, acc[j][i]);
                    acc[j][i] = fmaf(wv[j].y, xv[i].y, acc[j][i]);
                    acc[j][i] = fmaf(wv[j].z, xv[i].z, acc[j][i]);
                    acc[j][i] = fmaf(wv[j].w, xv[i].w, acc[j][i]);
                }
        }
    }
#pragma unroll
    for (int j = 0; j < 4; ++j) {
        int g = g0 + gq + 16*j;
        float bg = xb[g];
#pragma unroll
        for (int i = 0; i < 4; ++i) {
            int b = bq + 16*i;
            xp[((size_t)t * GG + g) * BB + b] = acc[j][i] + bg;
        }
    }
}

// ---------------- Phase B: persistent GRU scan (fence-free) ----------------
// 128 WGs x 512 threads, 1 WG/CU (LDS-limited). WG j owns H-cols [4j,4j+4).
// Cross-WG data path uses sc0|sc1 (coherence point = memory-side Infinity
// Cache) -> NO buffer_wbl2 / buffer_inv cache maintenance anywhere.
// Order: h stores (sc1) -> s_waitcnt vmcnt(0) -> __syncthreads -> tag store.
// Readers: poll tag (sc1) -> stage full h(t-1) into LDS (sc1 dwordx4).
__global__ __launch_bounds__(512)
void scan_kernel(const float* __restrict__ xp, const float* __restrict__ hw,
                 const float* __restrict__ hbias, float* __restrict__ rnn,
                 int* __restrict__ tags)
{
    __shared__ f32x4 wl4[12 * 129]; // weights: row (g*4+c), 128 f32x4 + pad
    __shared__ f32x4 hs4[64 * 129]; // h stage: row b, 128 f32x4 + pad
    const int j  = blockIdx.x;
    const int c0 = j * 4;
    const int tid = threadIdx.x;
    const int c    = tid & 3;
    const int half = (tid >> 2) & 1;
    const int b    = tid >> 3;

    const f32x4* hw4 = (const f32x4*)hw;
    for (int i = tid; i < 12 * 128; i += 512) {
        int row = i >> 7, x = i & 127;
        int g = row >> 2, cc = row & 3;
        wl4[row * 129 + x] = hw4[((size_t)g * HH + c0 + cc) * 128 + x];
    }
    const int col = c0 + c;
    const float bhr = hbias[col];
    const float bhu = hbias[HH + col];
    const float bhn = hbias[2 * HH + col];
    __syncthreads();

    const int hb = b * 129 + half * 64;
    const int w0 = (0 * 4 + c) * 129 + half * 64;
    const int w1 = (1 * 4 + c) * 129 + half * 64;
    const int w2 = (2 * 4 + c) * 129 + half * 64;

    long long budget = 2000000; // spin budget: bug -> wrong answer, not hang

    for (int t = 0; t < TT; ++t) {
        float xr = 0.f, xu = 0.f, xn = 0.f;
        if (t > 0) {
            if (tid < WSCAN) {
                const int* tp = tags + tid * TAGPAD;
                int v;
                do {
                    asm volatile("global_load_dword %0, %1, off sc0 sc1\n\t"
                                 "s_waitcnt vmcnt(0)"
                                 : "=v"(v) : "v"(tp) : "memory");
                } while (v < t && --budget > 0);
            }
            __syncthreads();
            // stage h(t-1): 128 KB, 512 thr x 16 f32x4, coalesced sc1 loads
            const float* hsrc = rnn + (size_t)(t - 1) * BB * HH;
            f32x4 tmp[16];
#pragma unroll
            for (int r = 0; r < 16; ++r) {
                const float* p = hsrc + (r * 512 + tid) * 4;
                asm volatile("global_load_dwordx4 %0, %1, off sc0 sc1"
                             : "=v"(tmp[r]) : "v"(p) : "memory");
            }
            if (half == 0) { // overlap xp loads with staging latency
                const size_t xbase = (size_t)t * GG * BB;
                xr = xp[xbase + (size_t)(0 * HH + col) * BB + b];
                xu = xp[xbase + (size_t)(1 * HH + col) * BB + b];
                xn = xp[xbase + (size_t)(2 * HH + col) * BB + b];
            }
            asm volatile("s_waitcnt vmcnt(0)" ::: "memory");
#pragma unroll
            for (int r = 0; r < 16; ++r) {
                int f = r * 512 + tid;
                hs4[(f >> 7) * 129 + (f & 127)] = tmp[r];
            }
            __syncthreads();
        } else {
            if (half == 0) {
                xr = xp[(size_t)(0 * HH + col) * BB + b];
                xu = xp[(size_t)(1 * HH + col) * BB + b];
                xn = xp[(size_t)(2 * HH + col) * BB + b];
            }
        }

        float ar = 0.f, au = 0.f, an = 0.f;
        float hprev = 0.f;
        if (t > 0) {
#pragma unroll 8
            for (int k4 = 0; k4 < 64; ++k4) {
                f32x4 h4 = hs4[hb + k4];
                f32x4 a4 = wl4[w0 + k4];
                f32x4 b4 = wl4[w1 + k4];
                f32x4 c4 = wl4[w2 + k4];
                ar = fmaf(h4.x, a4.x, ar); ar = fmaf(h4.y, a4.y, ar);
                ar = fmaf(h4.z, a4.z, ar); ar = fmaf(h4.w, a4.w, ar);
                au = fmaf(h4.x, b4.x, au); au = fmaf(h4.y, b4.y, au);
                au = fmaf(h4.z, b4.z, au); au = fmaf(h4.w, b4.w, au);
                an = fmaf(h4.x, c4.x, an); an = fmaf(h4.y, c4.y, an);
                an = fmaf(h4.z, c4.z, an); an = fmaf(h4.w, c4.w, an);
            }
            ar += __shfl_xor(ar, 4, 64);
            au += __shfl_xor(au, 4, 64);
            an += __shfl_xor(an, 4, 64);
            if (half == 0)
                hprev = ((const float*)hs4)[b * 516 + col];
        }

        if (half == 0) {
            float r = 1.f / (1.f + __expf(-(xr + ar + bhr)));
            float u = 1.f / (1.f + __expf(-(xu + au + bhu)));
            // h2h bias of n-gate sits INSIDE reset*(...), per reference
            float npre = xn + r * (an + bhn);
            float e  = __expf(-2.f * npre);
            float nv = 2.f / (1.f + e) - 1.f;
            float hy = u * hprev + (1.f - u) * nv;
            float* dst = rnn + ((size_t)t * BB + b) * HH + col;
            asm volatile("global_store_dword %0, %1, off sc0 sc1"
                         :: "v"(dst), "v"(hy) : "memory");
        }
        asm volatile("s_waitcnt vmcnt(0)" ::: "memory");
        __syncthreads();
        if (tid == 0) {
            int tv = t + 1;
            int* tp = tags + j * TAGPAD;
            asm volatile("global_store_dword %0, %1, off sc0 sc1"
                         :: "v"(tp), "v"(tv) : "memory");
        }
    }
}

// ---------------- Phase C: fc output ----------------
__global__ __launch_bounds__(256)
void fc_kernel(const float* __restrict__ rnn, const float* __restrict__ fcw,
               const float* __restrict__ fcb, float* __restrict__ out)
{
    __shared__ float wlds[128][65];
    const int t = blockIdx.x;
    const int tid = threadIdx.x;
    const int o  = tid & 63;
    const int bg = tid >> 6;
    float acc[16];
#pragma unroll
    for (int i = 0; i < 16; ++i) acc[i] = 0.f;

    for (int kc = 0; kc < 4; ++kc) {
        const int k0 = kc * 128;
        __syncthreads();
        for (int idx = tid; idx < 64 * 32; idx += 256) {
            int oo = idx >> 5, kq = (idx & 31) * 4;
            float4 v = *(const float4*)(fcw + (size_t)oo * HH + k0 + kq);
            wlds[kq][oo] = v.x; wlds[kq+1][oo] = v.y;
            wlds[kq+2][oo] = v.z; wlds[kq+3][oo] = v.w;
        }
        __syncthreads();
#pragma unroll 2
        for (int k4 = 0; k4 < 32; ++k4) {
            float w0 = wlds[k4*4+0][o], w1 = wlds[k4*4+1][o];
            float w2 = wlds[k4*4+2][o], w3 = wlds[k4*4+3][o];
#pragma unroll
            for (int i = 0; i < 16; ++i) {
                int bb = bg * 16 + i;
                float4 h4 = *(const float4*)(rnn + ((size_t)t * BB + bb) * HH + k0 + k4*4);
                acc[i] = fmaf(h4.x, w0, fmaf(h4.y, w1, fmaf(h4.z, w2, fmaf(h4.w, w3, acc[i]))));
            }
        }
    }
    float bo = fcb[o];
#pragma unroll
    for (int i = 0; i < 16; ++i) {
        int bb = bg * 16 + i;
        out[((size_t)t * BB + bb) * OO + o] = acc[i] + bo;
    }
}

extern "C" void kernel_launch(void* const* d_in, const int* in_sizes, int n_in,
                              void* d_out, int out_size, void* d_ws, size_t ws_size,
                              hipStream_t stream)
{
    const float* x     = (const float*)d_in[0];
    const float* x2h_w = (const float*)d_in[1];
    const float* x2h_b = (const float*)d_in[2];
    const float* h2h_w = (const float*)d_in[3];
    const float* h2h_b = (const float*)d_in[4];
    const float* fc_w  = (const float*)d_in[5];
    const float* fc_b  = (const float*)d_in[6];

    float* out = (float*)d_out;                        // [T][B][O]
    float* rnn = (float*)d_out + (size_t)TT * BB * OO; // [T][B][H]

    float* xp = (float*)d_ws;                          // [T][3H][B] fp32
    const size_t xp_bytes = (size_t)TT * GG * BB * sizeof(float);
    int* tags = (int*)((char*)d_ws + xp_bytes);

    hipMemsetAsync(tags, 0, WSCAN * TAGPAD * sizeof(int), stream);

    dim3 gA(GG / 64, TT);
    xproj_kernel<<<gA, 256, 0, stream>>>(x, x2h_w, x2h_b, xp);
    scan_kernel<<<WSCAN, 512, 0, stream>>>(xp, h2h_w, h2h_b, rnn, tags);
    fc_kernel<<<TT, 256, 0, stream>>>(rnn, fc_w, fc_b, out);
}

// Round 3
// 4569.823 us; speedup vs baseline: 3.9886x; 1.3563x over previous
//
#include <hip/hip_runtime.h>
#include <cstdint>
#include <cstddef>

#define TT 512
#define BB 64
#define II 256
#define HH 512
#define GG 1536   // 3*H
#define OO 64
#define WSCAN 256 // scan workgroups: all CUs, each owns NC columns
#define NC 2      // columns per WG (6 gate-rows)
#define TAGPAD 16 // dwords between tags (64B -> distinct LLC lines)

// ---------------- Phase A: x_proj ----------------
__global__ __launch_bounds__(256)
void xproj_kernel(const float* __restrict__ x, const float* __restrict__ w,
                  const float* __restrict__ xb, float* __restrict__ xp)
{
    __shared__ float xs[64][68];
    __shared__ float ws[64][68];
    const int t  = blockIdx.y;
    const int g0 = blockIdx.x * 64;
    const int tid = threadIdx.x;
    const int gq = tid >> 4;
    const int bq = tid & 15;
    float acc[4][4];
#pragma unroll
    for (int j = 0; j < 4; ++j)
#pragma unroll
        for (int i = 0; i < 4; ++i) acc[j][i] = 0.f;

    for (int kc = 0; kc < 4; ++kc) {
        const int k0 = kc * 64;
        __syncthreads();
        for (int idx = tid; idx < 1024; idx += 256) {
            int r = idx >> 4, c4 = (idx & 15) * 4;
            float4 v = *(const float4*)(x + ((size_t)t * BB + r) * II + k0 + c4);
            xs[r][c4] = v.x; xs[r][c4+1] = v.y; xs[r][c4+2] = v.z; xs[r][c4+3] = v.w;
            float4 u = *(const float4*)(w + (size_t)(g0 + r) * II + k0 + c4);
            ws[r][c4] = u.x; ws[r][c4+1] = u.y; ws[r][c4+2] = u.z; ws[r][c4+3] = u.w;
        }
        __syncthreads();
#pragma unroll 4
        for (int k4 = 0; k4 < 16; ++k4) {
            float4 xv[4], wv[4];
#pragma unroll
            for (int i = 0; i < 4; ++i)
                xv[i] = *(const float4*)&xs[bq + 16*i][k4*4];
#pragma unroll
            for (int j = 0; j < 4; ++j)
                wv[j] = *(const float4*)&ws[gq + 16*j][k4*4];
#pragma unroll
            for (int j = 0; j < 4; ++j)
#pragma unroll
                for (int i = 0; i < 4; ++i) {
                    acc[j][i] = fmaf(wv[j].x, xv[i].x, acc[j][i]);
                    acc[j][i] = fmaf(wv[j].y, xv[i].y, acc[j][i]);
                    acc[j][i] = fmaf(wv[j].z, xv[i].z, acc[j][i]);
                    acc[j][i] = fmaf(wv[j].w, xv[i].w, acc[j][i]);
                }
        }
    }
#pragma unroll
    for (int j = 0; j < 4; ++j) {
        int g = g0 + gq + 16*j;
        float bg = xb[g];
#pragma unroll
        for (int i = 0; i < 4; ++i) {
            int b = bq + 16*i;
            xp[((size_t)t * GG + g) * BB + b] = acc[j][i] + bg;
        }
    }
}

// ---------------- Phase B: persistent GRU scan ----------------
// 256 WGs x 512 thr (1/CU; total threads << capacity => always co-resident).
// WG j owns cols [2j, 2j+2) (6 gate-rows, resident in LDS).
// Exchange: producer stores h sc0|sc1 (coherence point = Infinity Cache);
// consumers read with NORMAL cached loads (L2 fills post-tag; h addresses are
// fresh each step => no stale lines; one __threadfence() at start drops
// poison lines). Register-tiled dot: thread (wave,bg,ks) does 8b x 6r x 8k.
__global__ __launch_bounds__(512, 2)
void scan_kernel(const float* __restrict__ xp, const float* __restrict__ hw,
                 const float* __restrict__ hbias, float* __restrict__ rnn,
                 int* __restrict__ tags)
{
    __shared__ float wl[6][520];        // weight rows r = gate*NC+c
    __shared__ float part[64 * 6 * 9];  // [b][r][wave] stride 9
    const int j   = blockIdx.x;
    const int c0  = j * NC;
    const int tid = threadIdx.x;
    const int wave = tid >> 6;
    const int lane = tid & 63;
    const int bg   = lane >> 3;
    const int ks   = lane & 7;
    const int kbase = wave * 64 + ks * 8;

    if (tid == 0) __threadfence(); // one-time L2 wb+inv: drop stale/poison lines
    __syncthreads();

    // stage 6 weight rows (12 KB)
    for (int i = tid; i < 6 * 128; i += 512) {
        int r = i >> 7, q = (i & 127) * 4;
        int gate = r / NC, cc = r % NC;
        float4 v = *(const float4*)(hw + ((size_t)gate * HH + c0 + cc) * HH + q);
        *(float4*)&wl[r][q] = v;
    }
    const int ob = tid & 63;          // output-phase b
    const int oc = tid >> 6;          // output-phase c (only tid<128 used)
    const int ocol = c0 + oc;
    float bhr = 0.f, bhu = 0.f, bhn = 0.f;
    if (tid < 128) {
        bhr = hbias[ocol]; bhu = hbias[HH + ocol]; bhn = hbias[2 * HH + ocol];
    }
    __syncthreads();

    float hloc = 0.f;            // tid<128: my (b,c) previous h (fp32, exact)
    long long budget = 4000000;  // spin bound: bug -> wrong answer, not hang

    for (int t = 0; t < TT; ++t) {
        if (t > 0 && tid < WSCAN) {
            const int* tp = tags + tid * TAGPAD;
            int v;
            do {
                asm volatile("global_load_dword %0, %1, off sc0 sc1\n\t"
                             "s_waitcnt vmcnt(0)"
                             : "=v"(v) : "v"(tp) : "memory");
                if (v >= t) break;
                __builtin_amdgcn_s_sleep(1);
            } while (--budget > 0);
        }
        __syncthreads(); // B1 (also separates prev part[] reads from writes)

        if (t > 0) {
            // h loads: 8 b x 8 k, normal cached (L2 serves after first fill)
            float4 h4[8][2];
            const float* hsrc = rnn + (size_t)(t - 1) * BB * HH + kbase;
#pragma unroll
            for (int bi = 0; bi < 8; ++bi) {
                const float* p = hsrc + (size_t)(bg * 8 + bi) * HH;
                h4[bi][0] = *(const float4*)p;
                h4[bi][1] = *(const float4*)(p + 4);
            }
            float acc[8][6];
#pragma unroll
            for (int r = 0; r < 6; ++r) {
                const float4 w0 = *(const float4*)&wl[r][kbase];
                const float4 w1 = *(const float4*)&wl[r][kbase + 4];
#pragma unroll
                for (int bi = 0; bi < 8; ++bi) {
                    float a;
                    a = h4[bi][0].x * w0.x;
                    a = fmaf(h4[bi][0].y, w0.y, a);
                    a = fmaf(h4[bi][0].z, w0.z, a);
                    a = fmaf(h4[bi][0].w, w0.w, a);
                    a = fmaf(h4[bi][1].x, w1.x, a);
                    a = fmaf(h4[bi][1].y, w1.y, a);
                    a = fmaf(h4[bi][1].z, w1.z, a);
                    a = fmaf(h4[bi][1].w, w1.w, a);
                    acc[bi][r] = a;
                }
            }
            // butterfly over the 8 ks-lanes (lane bits 0..2)
#pragma unroll
            for (int bi = 0; bi < 8; ++bi)
#pragma unroll
                for (int r = 0; r < 6; ++r) {
                    float v = acc[bi][r];
                    v += __shfl_xor(v, 1, 64);
                    v += __shfl_xor(v, 2, 64);
                    v += __shfl_xor(v, 4, 64);
                    acc[bi][r] = v;
                }
            // lane (bg,ks) publishes acc[ks][r] via compile-time select tree
#pragma unroll
            for (int r = 0; r < 6; ++r) {
                float s01 = (ks & 1) ? acc[1][r] : acc[0][r];
                float s23 = (ks & 1) ? acc[3][r] : acc[2][r];
                float s45 = (ks & 1) ? acc[5][r] : acc[4][r];
                float s67 = (ks & 1) ? acc[7][r] : acc[6][r];
                float sA  = (ks & 2) ? s23 : s01;
                float sB  = (ks & 2) ? s67 : s45;
                float sel = (ks & 4) ? sB : sA;
                part[((bg * 8 + ks) * 6 + r) * 9 + wave] = sel;
            }
        }
        __syncthreads(); // B2

        if (tid < 128) {
            float ar = 0.f, au = 0.f, an = 0.f;
            if (t > 0) {
#pragma unroll
                for (int w = 0; w < 8; ++w) {
                    ar += part[(ob * 6 + (0 * NC + oc)) * 9 + w];
                    au += part[(ob * 6 + (1 * NC + oc)) * 9 + w];
                    an += part[(ob * 6 + (2 * NC + oc)) * 9 + w];
                }
            }
            const size_t xbase = (size_t)t * GG * BB;
            float xr = xp[xbase + (size_t)(0 * HH + ocol) * BB + ob];
            float xu = xp[xbase + (size_t)(1 * HH + ocol) * BB + ob];
            float xn = xp[xbase + (size_t)(2 * HH + ocol) * BB + ob];
            float r = 1.f / (1.f + __expf(-(xr + ar + bhr)));
            float u = 1.f / (1.f + __expf(-(xu + au + bhu)));
            // h2h bias of n-gate sits INSIDE reset*(...), per reference
            float npre = xn + r * (an + bhn);
            float e  = __expf(-2.f * npre);
            float nv = 2.f / (1.f + e) - 1.f;
            float hy = u * hloc + (1.f - u) * nv;
            hloc = hy;
            float* dst = rnn + ((size_t)t * BB + ob) * HH + ocol;
            asm volatile("global_store_dword %0, %1, off sc0 sc1"
                         :: "v"(dst), "v"(hy) : "memory");
        }
        asm volatile("s_waitcnt vmcnt(0)" ::: "memory");
        __syncthreads(); // B3
        if (tid == 0) {
            int tv = t + 1;
            int* tp = tags + j * TAGPAD;
            asm volatile("global_store_dword %0, %1, off sc0 sc1"
                         :: "v"(tp), "v"(tv) : "memory");
        }
    }
}

// ---------------- Phase C: fc output ----------------
__global__ __launch_bounds__(256)
void fc_kernel(const float* __restrict__ rnn, const float* __restrict__ fcw,
               const float* __restrict__ fcb, float* __restrict__ out)
{
    __shared__ float wlds[128][65];
    const int t = blockIdx.x;
    const int tid = threadIdx.x;
    const int o  = tid & 63;
    const int bg = tid >> 6;
    float acc[16];
#pragma unroll
    for (int i = 0; i < 16; ++i) acc[i] = 0.f;

    for (int kc = 0; kc < 4; ++kc) {
        const int k0 = kc * 128;
        __syncthreads();
        for (int idx = tid; idx < 64 * 32; idx += 256) {
            int oo = idx >> 5, kq = (idx & 31) * 4;
            float4 v = *(const float4*)(fcw + (size_t)oo * HH + k0 + kq);
            wlds[kq][oo] = v.x; wlds[kq+1][oo] = v.y;
            wlds[kq+2][oo] = v.z; wlds[kq+3][oo] = v.w;
        }
        __syncthreads();
#pragma unroll 2
        for (int k4 = 0; k4 < 32; ++k4) {
            float w0 = wlds[k4*4+0][o], w1 = wlds[k4*4+1][o];
            float w2 = wlds[k4*4+2][o], w3 = wlds[k4*4+3][o];
#pragma unroll
            for (int i = 0; i < 16; ++i) {
                int bb = bg * 16 + i;
                float4 h4 = *(const float4*)(rnn + ((size_t)t * BB + bb) * HH + k0 + k4*4);
                acc[i] = fmaf(h4.x, w0, fmaf(h4.y, w1, fmaf(h4.z, w2, fmaf(h4.w, w3, acc[i]))));
            }
        }
    }
    float bo = fcb[o];
#pragma unroll
    for (int i = 0; i < 16; ++i) {
        int bb = bg * 16 + i;
        out[((size_t)t * BB + bb) * OO + o] = acc[i] + bo;
    }
}

extern "C" void kernel_launch(void* const* d_in, const int* in_sizes, int n_in,
                              void* d_out, int out_size, void* d_ws, size_t ws_size,
                              hipStream_t stream)
{
    const float* x     = (const float*)d_in[0];
    const float* x2h_w = (const float*)d_in[1];
    const float* x2h_b = (const float*)d_in[2];
    const float* h2h_w = (const float*)d_in[3];
    const float* h2h_b = (const float*)d_in[4];
    const float* fc_w  = (const float*)d_in[5];
    const float* fc_b  = (const float*)d_in[6];

    float* out = (float*)d_out;                        // [T][B][O]
    float* rnn = (float*)d_out + (size_t)TT * BB * OO; // [T][B][H]

    float* xp = (float*)d_ws;                          // [T][3H][B] fp32
    const size_t xp_bytes = (size_t)TT * GG * BB * sizeof(float);
    int* tags = (int*)((char*)d_ws + xp_bytes);

    hipMemsetAsync(tags, 0, WSCAN * TAGPAD * sizeof(int), stream);

    dim3 gA(GG / 64, TT);
    xproj_kernel<<<gA, 256, 0, stream>>>(x, x2h_w, x2h_b, xp);
    scan_kernel<<<WSCAN, 512, 0, stream>>>(xp, h2h_w, h2h_b, rnn, tags);
    fc_kernel<<<TT, 256, 0, stream>>>(rnn, fc_w, fc_b, out);
}

// Round 4
// 3148.844 us; speedup vs baseline: 5.7885x; 1.4513x over previous
//
#include <hip/hip_runtime.h>
#include <cstdint>
#include <cstddef>

#define TT 512
#define BB 64
#define II 256
#define HH 512
#define GG 1536   // 3*H
#define OO 64
#define WSCAN 256 // scan workgroups: one per CU, each owns NC columns
#define NC 2      // columns per WG (6 gate-rows)
#define TAGPAD 16 // dwords between tags (64B -> distinct LLC lines)

// ---------------- Phase A: x_proj ----------------
__global__ __launch_bounds__(256)
void xproj_kernel(const float* __restrict__ x, const float* __restrict__ w,
                  const float* __restrict__ xb, float* __restrict__ xp)
{
    __shared__ float xs[64][68];
    __shared__ float ws[64][68];
    const int t  = blockIdx.y;
    const int g0 = blockIdx.x * 64;
    const int tid = threadIdx.x;
    const int gq = tid >> 4;
    const int bq = tid & 15;
    float acc[4][4];
#pragma unroll
    for (int j = 0; j < 4; ++j)
#pragma unroll
        for (int i = 0; i < 4; ++i) acc[j][i] = 0.f;

    for (int kc = 0; kc < 4; ++kc) {
        const int k0 = kc * 64;
        __syncthreads();
        for (int idx = tid; idx < 1024; idx += 256) {
            int r = idx >> 4, c4 = (idx & 15) * 4;
            float4 v = *(const float4*)(x + ((size_t)t * BB + r) * II + k0 + c4);
            xs[r][c4] = v.x; xs[r][c4+1] = v.y; xs[r][c4+2] = v.z; xs[r][c4+3] = v.w;
            float4 u = *(const float4*)(w + (size_t)(g0 + r) * II + k0 + c4);
            ws[r][c4] = u.x; ws[r][c4+1] = u.y; ws[r][c4+2] = u.z; ws[r][c4+3] = u.w;
        }
        __syncthreads();
#pragma unroll 4
        for (int k4 = 0; k4 < 16; ++k4) {
            float4 xv[4], wv[4];
#pragma unroll
            for (int i = 0; i < 4; ++i)
                xv[i] = *(const float4*)&xs[bq + 16*i][k4*4];
#pragma unroll
            for (int j = 0; j < 4; ++j)
                wv[j] = *(const float4*)&ws[gq + 16*j][k4*4];
#pragma unroll
            for (int j = 0; j < 4; ++j)
#pragma unroll
                for (int i = 0; i < 4; ++i) {
                    acc[j][i] = fmaf(wv[j].x, xv[i].x, acc[j][i]);
                    acc[j][i] = fmaf(wv[j].y, xv[i].y, acc[j][i]);
                    acc[j][i] = fmaf(wv[j].z, xv[i].z, acc[j][i]);
                    acc[j][i] = fmaf(wv[j].w, xv[i].w, acc[j][i]);
                }
        }
    }
#pragma unroll
    for (int j = 0; j < 4; ++j) {
        int g = g0 + gq + 16*j;
        float bg = xb[g];
#pragma unroll
        for (int i = 0; i < 4; ++i) {
            int b = bq + 16*i;
            xp[((size_t)t * GG + g) * BB + b] = acc[j][i] + bg;
        }
    }
}

// ---------------- Phase B: persistent GRU scan (register-resident) --------
// 256 WGs x 512 thr (1/CU). WG j owns cols [2j,2j+2): 6 gate-rows x 512 k
// = 48 floats/thread held in VGPRs (zero LDS). Wave w owns b-block w*8..+8;
// lane l covers k in [8l,8l+8) for all 8 b x 6 rows (384 FMA). k-reduction:
// recursive-halving transpose-reduce (51 shuffles/thread, no LDS, no extra
// barrier). Exchange protocol identical to r3 (sc0|sc1 stores to IC, tag
// release after vmcnt drain; consumers read h with normal cached loads).
__global__ __launch_bounds__(512, 2)
void scan_kernel(const float* __restrict__ xp, const float* __restrict__ hw,
                 const float* __restrict__ hbias, float* __restrict__ rnn,
                 int* __restrict__ tags)
{
    const int j   = blockIdx.x;
    const int c0  = j * NC;
    const int tid = threadIdx.x;
    const int w   = tid >> 6;       // wave: b-block
    const int l   = tid & 63;       // lane: k-chunk [8l, 8l+8)
    const int bblk = w * 8;
    const int k0   = l * 8;
    const int cc   = (l >> 3) & 1;  // epilogue c (valid pattern for all l)
    const int col  = c0 + cc;
    const int ob   = bblk + (l & 7);// epilogue b

    if (tid == 0) __threadfence(); // one-time L2 wb+inv: drop poison lines
    __syncthreads();

    // weights -> registers: rr = gate*NC + c, k in [k0, k0+8)
    float wreg[6][8];
#pragma unroll
    for (int rr = 0; rr < 6; ++rr) {
        const float* wp = hw + ((size_t)(rr >> 1) * HH + c0 + (rr & 1)) * HH + k0;
        float4 a = *(const float4*)wp;
        float4 b = *(const float4*)(wp + 4);
        wreg[rr][0] = a.x; wreg[rr][1] = a.y; wreg[rr][2] = a.z; wreg[rr][3] = a.w;
        wreg[rr][4] = b.x; wreg[rr][5] = b.y; wreg[rr][6] = b.z; wreg[rr][7] = b.w;
    }
    const float bhr = hbias[col];
    const float bhu = hbias[HH + col];
    const float bhn = hbias[2 * HH + col];

    float hloc = 0.f;            // lanes l<16: my (b,c) previous h (exact fp32)
    long long budget = 4000000;  // spin bound: bug -> wrong answer, not hang

    for (int t = 0; t < TT; ++t) {
        // xp prefetch for this step (independent of h) - hide HBM latency
        float xr = 0.f, xu = 0.f, xn = 0.f;
        if (l < 16) {
            const size_t xbase = (size_t)t * GG * BB;
            xr = xp[xbase + (size_t)(0 * HH + col) * BB + ob];
            xu = xp[xbase + (size_t)(1 * HH + col) * BB + ob];
            xn = xp[xbase + (size_t)(2 * HH + col) * BB + ob];
        }

        float g0v = 0.f, g1v = 0.f, g2v = 0.f;
        if (t > 0) {
            if (tid < WSCAN) {
                const int* tp = tags + tid * TAGPAD;
                int v;
                do {
                    asm volatile("global_load_dword %0, %1, off sc0 sc1\n\t"
                                 "s_waitcnt vmcnt(0)"
                                 : "=v"(v) : "v"(tp) : "memory");
                    if (v >= t) break;
                    __builtin_amdgcn_s_sleep(1);
                } while (--budget > 0);
            }
            __syncthreads(); // B1: all tags seen -> h(t-1) complete at IC

            // h loads: 8 b x 8 k, coalesced (lane l -> 32B at k0=8l)
            const float* hsrc = rnn + (size_t)(t - 1) * BB * HH + k0;
            float4 h4[8][2];
#pragma unroll
            for (int bi = 0; bi < 8; ++bi) {
                const float* p = hsrc + (size_t)(bblk + bi) * HH;
                h4[bi][0] = *(const float4*)p;
                h4[bi][1] = *(const float4*)(p + 4);
            }
            float acc[8][6];
#pragma unroll
            for (int bi = 0; bi < 8; ++bi)
#pragma unroll
                for (int rr = 0; rr < 6; ++rr) {
                    float a;
                    a = h4[bi][0].x * wreg[rr][0];
                    a = fmaf(h4[bi][0].y, wreg[rr][1], a);
                    a = fmaf(h4[bi][0].z, wreg[rr][2], a);
                    a = fmaf(h4[bi][0].w, wreg[rr][3], a);
                    a = fmaf(h4[bi][1].x, wreg[rr][4], a);
                    a = fmaf(h4[bi][1].y, wreg[rr][5], a);
                    a = fmaf(h4[bi][1].z, wreg[rr][6], a);
                    a = fmaf(h4[bi][1].w, wreg[rr][7], a);
                    acc[bi][rr] = a;
                }

            // transpose-reduce: round 1 (b bit0, mask 1)
            const int s0 = l & 1, s1 = (l >> 1) & 1, s2 = (l >> 2) & 1;
            const int s3 = (l >> 3) & 1;
            float a1[4][6];
#pragma unroll
            for (int rr = 0; rr < 6; ++rr)
#pragma unroll
                for (int p = 0; p < 4; ++p) {
                    float lo = acc[2*p][rr], hi = acc[2*p+1][rr];
                    float send = s0 ? lo : hi;
                    float keep = s0 ? hi : lo;
                    a1[p][rr] = keep + __shfl_xor(send, 1, 64);
                }
            // round 2 (b bit1, mask 2)
            float a2[2][6];
#pragma unroll
            for (int rr = 0; rr < 6; ++rr)
#pragma unroll
                for (int p = 0; p < 2; ++p) {
                    float lo = a1[2*p][rr], hi = a1[2*p+1][rr];
                    float send = s1 ? lo : hi;
                    float keep = s1 ? hi : lo;
                    a2[p][rr] = keep + __shfl_xor(send, 2, 64);
                }
            // round 3 (b bit2, mask 4)
            float a3[6];
#pragma unroll
            for (int rr = 0; rr < 6; ++rr) {
                float lo = a2[0][rr], hi = a2[1][rr];
                float send = s2 ? lo : hi;
                float keep = s2 ? hi : lo;
                a3[rr] = keep + __shfl_xor(send, 4, 64);
            }
            // round 4 (c split, mask 8)
#pragma unroll
            for (int gate = 0; gate < 3; ++gate) {
                float lo = a3[2*gate], hi = a3[2*gate + 1];
                float send = s3 ? lo : hi;
                float keep = s3 ? hi : lo;
                float gv = keep + __shfl_xor(send, 8, 64);
                if (gate == 0) g0v = gv; else if (gate == 1) g1v = gv; else g2v = gv;
            }
            // rounds 5,6: butterfly masks 16, 32 -> full k-sum
            g0v += __shfl_xor(g0v, 16, 64); g0v += __shfl_xor(g0v, 32, 64);
            g1v += __shfl_xor(g1v, 16, 64); g1v += __shfl_xor(g1v, 32, 64);
            g2v += __shfl_xor(g2v, 16, 64); g2v += __shfl_xor(g2v, 32, 64);
        }

        if (l < 16) { // one lane per output (b=ob, c=cc)
            float r = 1.f / (1.f + __expf(-(xr + g0v + bhr)));
            float u = 1.f / (1.f + __expf(-(xu + g1v + bhu)));
            // h2h bias of n-gate sits INSIDE reset*(...), per reference
            float npre = xn + r * (g2v + bhn);
            float e  = __expf(-2.f * npre);
            float nv = 2.f / (1.f + e) - 1.f;
            float hy = u * hloc + (1.f - u) * nv;
            hloc = hy;
            float* dst = rnn + ((size_t)t * BB + ob) * HH + col;
            asm volatile("global_store_dword %0, %1, off sc0 sc1"
                         :: "v"(dst), "v"(hy) : "memory");
        }
        asm volatile("s_waitcnt vmcnt(0)" ::: "memory");
        __syncthreads(); // B3: all h stores acked at IC
        if (tid == 0) {
            int tv = t + 1;
            int* tp = tags + j * TAGPAD;
            asm volatile("global_store_dword %0, %1, off sc0 sc1"
                         :: "v"(tp), "v"(tv) : "memory");
        }
    }
}

// ---------------- Phase C: fc output ----------------
__global__ __launch_bounds__(256)
void fc_kernel(const float* __restrict__ rnn, const float* __restrict__ fcw,
               const float* __restrict__ fcb, float* __restrict__ out)
{
    __shared__ float wlds[128][65];
    const int t = blockIdx.x;
    const int tid = threadIdx.x;
    const int o  = tid & 63;
    const int bg = tid >> 6;
    float acc[16];
#pragma unroll
    for (int i = 0; i < 16; ++i) acc[i] = 0.f;

    for (int kc = 0; kc < 4; ++kc) {
        const int k0 = kc * 128;
        __syncthreads();
        for (int idx = tid; idx < 64 * 32; idx += 256) {
            int oo = idx >> 5, kq = (idx & 31) * 4;
            float4 v = *(const float4*)(fcw + (size_t)oo * HH + k0 + kq);
            wlds[kq][oo] = v.x; wlds[kq+1][oo] = v.y;
            wlds[kq+2][oo] = v.z; wlds[kq+3][oo] = v.w;
        }
        __syncthreads();
#pragma unroll 2
        for (int k4 = 0; k4 < 32; ++k4) {
            float w0 = wlds[k4*4+0][o], w1 = wlds[k4*4+1][o];
            float w2 = wlds[k4*4+2][o], w3 = wlds[k4*4+3][o];
#pragma unroll
            for (int i = 0; i < 16; ++i) {
                int bb = bg * 16 + i;
                float4 h4 = *(const float4*)(rnn + ((size_t)t * BB + bb) * HH + k0 + k4*4);
                acc[i] = fmaf(h4.x, w0, fmaf(h4.y, w1, fmaf(h4.z, w2, fmaf(h4.w, w3, acc[i]))));
            }
        }
    }
    float bo = fcb[o];
#pragma unroll
    for (int i = 0; i < 16; ++i) {
        int bb = bg * 16 + i;
        out[((size_t)t * BB + bb) * OO + o] = acc[i] + bo;
    }
}

extern "C" void kernel_launch(void* const* d_in, const int* in_sizes, int n_in,
                              void* d_out, int out_size, void* d_ws, size_t ws_size,
                              hipStream_t stream)
{
    const float* x     = (const float*)d_in[0];
    const float* x2h_w = (const float*)d_in[1];
    const float* x2h_b = (const float*)d_in[2];
    const float* h2h_w = (const float*)d_in[3];
    const float* h2h_b = (const float*)d_in[4];
    const float* fc_w  = (const float*)d_in[5];
    const float* fc_b  = (const float*)d_in[6];

    float* out = (float*)d_out;                        // [T][B][O]
    float* rnn = (float*)d_out + (size_t)TT * BB * OO; // [T][B][H]

    float* xp = (float*)d_ws;                          // [T][3H][B] fp32
    const size_t xp_bytes = (size_t)TT * GG * BB * sizeof(float);
    int* tags = (int*)((char*)d_ws + xp_bytes);

    hipMemsetAsync(tags, 0, WSCAN * TAGPAD * sizeof(int), stream);

    dim3 gA(GG / 64, TT);
    xproj_kernel<<<gA, 256, 0, stream>>>(x, x2h_w, x2h_b, xp);
    scan_kernel<<<WSCAN, 512, 0, stream>>>(xp, h2h_w, h2h_b, rnn, tags);
    fc_kernel<<<TT, 256, 0, stream>>>(rnn, fc_w, fc_b, out);
}